// Round 1
// baseline (783.692 us; speedup 1.0000x reference)
//
#include <hip/hip_runtime.h>
#include <hip/hip_bf16.h>

// Problem constants (fixed by setup_inputs)
#define Bq 2
#define Tq 2048
#define Cq 1024
#define Hq 16
#define Dq 64
#define N3C 3072
#define NROW (Bq * Tq)   // 4096

__device__ __forceinline__ float elu1(float x) {
    return x > 0.0f ? x + 1.0f : __expf(x);
}

// ---------------- RoPE cos/sin table (fp64 for accuracy) ----------------
__global__ void rope_table_kernel(float* __restrict__ cosT, float* __restrict__ sinT) {
    int idx = blockIdx.x * blockDim.x + threadIdx.x;   // T*32
    if (idx >= Tq * 32) return;
    int t = idx >> 5;
    int i = idx & 31;
    double inv = pow(10000.0, -(double)i / 32.0);
    double ang = (double)t * inv;
    cosT[idx] = (float)cos(ang);
    sinT[idx] = (float)sin(ang);
}

// ---------------- fp32 tiled GEMM with bias: C = A[M,K] @ B[K,N] + bias ----------------
// BM=BN=64, BK=16, 256 threads, 4x4 microtile per thread
#define BM 64
#define BN 64
#define BK 16
#define TM 4
#define TN 4
__global__ __launch_bounds__(256) void gemm_bias_kernel(
        const float* __restrict__ A, const float* __restrict__ B,
        const float* __restrict__ bias, float* __restrict__ C,
        int M, int N, int K) {
    __shared__ float As[BK][BM + 4];
    __shared__ float Bs[BK][BN + 4];
    const int tid = threadIdx.x;
    const int tx = tid & 15;        // 0..15 -> col group
    const int ty = tid >> 4;        // 0..15 -> row group
    const int brow = blockIdx.y * BM;
    const int bcol = blockIdx.x * BN;

    float acc[TM][TN] = {};

    for (int k0 = 0; k0 < K; k0 += BK) {
        #pragma unroll
        for (int i = 0; i < (BM * BK) / 256; ++i) {
            int idx = tid + i * 256;
            int r = idx / BK, c = idx % BK;
            As[c][r] = A[(size_t)(brow + r) * K + k0 + c];
        }
        #pragma unroll
        for (int i = 0; i < (BN * BK) / 256; ++i) {
            int idx = tid + i * 256;
            int r = idx / BN, c = idx % BN;
            Bs[r][c] = B[(size_t)(k0 + r) * N + bcol + c];
        }
        __syncthreads();
        #pragma unroll
        for (int kk = 0; kk < BK; ++kk) {
            float a[TM], b[TN];
            #pragma unroll
            for (int i = 0; i < TM; ++i) a[i] = As[kk][ty * TM + i];
            #pragma unroll
            for (int j = 0; j < TN; ++j) b[j] = Bs[kk][tx * TN + j];
            #pragma unroll
            for (int i = 0; i < TM; ++i)
                #pragma unroll
                for (int j = 0; j < TN; ++j)
                    acc[i][j] += a[i] * b[j];
        }
        __syncthreads();
    }
    #pragma unroll
    for (int i = 0; i < TM; ++i) {
        int r = brow + ty * TM + i;
        #pragma unroll
        for (int j = 0; j < TN; ++j) {
            int c = bcol + tx * TN + j;
            C[(size_t)r * N + c] = acc[i][j] + bias[c];
        }
    }
}

// ---------------- elu+1 then RoPE for Q and K ----------------
// grid: B*T blocks, 256 threads; each block does one row (16 heads x 64 dims)
__global__ __launch_bounds__(256) void qk_rope_kernel(
        const float* __restrict__ qkv, const float* __restrict__ cosT,
        const float* __restrict__ sinT, float* __restrict__ Qr,
        float* __restrict__ Kr) {
    int row = blockIdx.x;          // b*T + t
    int t = row & (Tq - 1);
    const float* q = qkv + (size_t)row * N3C;
    #pragma unroll
    for (int i = 0; i < 4; ++i) {
        int idx = threadIdx.x + i * 256;      // 0..1023 = h*64+d
        int d = idx & 63;
        int p = (d < 32) ? idx + 32 : idx - 32;
        float c = cosT[t * 32 + (d & 31)];
        float s = sinT[t * 32 + (d & 31)];
        float sgn = (d < 32) ? -1.0f : 1.0f;
        float qv = elu1(q[idx]);
        float qp = elu1(q[p]);
        float kv = elu1(q[Cq + idx]);
        float kp = elu1(q[Cq + p]);
        Qr[(size_t)row * Cq + idx] = qv * c + sgn * qp * s;
        Kr[(size_t)row * Cq + idx] = kv * c + sgn * kp * s;
    }
}

// ---------------- K_sum[b,h,d] = sum_t elu1(K) (deterministic) ----------------
// grid: B*H blocks, 256 threads (4 waves), lane = d
__global__ __launch_bounds__(256) void ksum_kernel(
        const float* __restrict__ qkv, float* __restrict__ Ksum) {
    int bh = blockIdx.x;
    int b = bh >> 4, h = bh & 15;
    int lane = threadIdx.x & 63, w = threadIdx.x >> 6;
    float s = 0.0f;
    for (int t = w; t < Tq; t += 4)
        s += elu1(qkv[((size_t)(b * Tq + t)) * N3C + Cq + h * 64 + lane]);
    __shared__ float red[4][64];
    red[w][lane] = s;
    __syncthreads();
    if (w == 0)
        Ksum[bh * 64 + lane] = red[0][lane] + red[1][lane] + red[2][lane] + red[3][lane];
}

// ---------------- denom[b,h,t] = dot(elu1(Q[b,t,h,:]), Ksum[b,h,:]) ----------------
// grid: B*T blocks, 256 threads = 4 waves; each wave does 4 heads
__global__ __launch_bounds__(256) void denom_kernel(
        const float* __restrict__ qkv, const float* __restrict__ Ksum,
        float* __restrict__ denom) {
    int row = blockIdx.x;
    int b = row >> 11;            // /2048
    int t = row & (Tq - 1);
    int lane = threadIdx.x & 63, w = threadIdx.x >> 6;
    #pragma unroll
    for (int hi = 0; hi < 4; ++hi) {
        int h = w * 4 + hi;
        float v = elu1(qkv[(size_t)row * N3C + h * 64 + lane]) * Ksum[(b * Hq + h) * 64 + lane];
        #pragma unroll
        for (int off = 32; off; off >>= 1) v += __shfl_down(v, off);
        if (lane == 0) denom[(size_t)(b * Hq + h) * Tq + t] = v;
    }
}

// ---------------- KV partial: KVpart[bh,ch,d,e] = sum_{t in chunk} Kr[t,d]*V[t,e] ----------------
#define NCH 16
#define CHT (Tq / NCH)    // 128
__global__ __launch_bounds__(256) void kv_kernel(
        const float* __restrict__ qkv, const float* __restrict__ Kr,
        float* __restrict__ KVpart) {
    int blk = blockIdx.x;                 // bh*NCH + ch
    int bh = blk / NCH, ch = blk % NCH;
    int b = bh >> 4, h = bh & 15;
    int e = threadIdx.x & 63;
    int dq = threadIdx.x >> 6;            // 0..3 -> d in [dq*16, dq*16+16)
    float acc[16] = {};
    __shared__ float sh[128];
    for (int tt = 0; tt < CHT; ++tt) {
        int t = ch * CHT + tt;
        size_t row = (size_t)(b * Tq + t);
        if (threadIdx.x < 64)
            sh[threadIdx.x] = Kr[row * Cq + h * 64 + threadIdx.x];
        else if (threadIdx.x < 128)
            sh[threadIdx.x] = qkv[row * N3C + 2 * Cq + h * 64 + (threadIdx.x - 64)];
        __syncthreads();
        float vv = sh[64 + e];
        #pragma unroll
        for (int i = 0; i < 16; ++i) acc[i] += sh[dq * 16 + i] * vv;
        __syncthreads();
    }
    float* out = KVpart + (size_t)blk * 4096;
    #pragma unroll
    for (int i = 0; i < 16; ++i) out[(dq * 16 + i) * 64 + e] = acc[i];
}

// ---------------- KV reduce over chunks ----------------
__global__ __launch_bounds__(256) void kv_reduce_kernel(
        const float* __restrict__ KVpart, float* __restrict__ KV) {
    int idx = blockIdx.x * 256 + threadIdx.x;    // < B*H*4096 = 131072
    int bh = idx >> 12;
    int i = idx & 4095;
    float s = 0.0f;
    #pragma unroll
    for (int ch = 0; ch < NCH; ++ch) s += KVpart[((size_t)(bh * NCH + ch)) * 4096 + i];
    KV[idx] = s;
}

// ---------------- y[b,t,h,e] = (sum_d Qr[t,d]*KV[d,e]) / denom[b,h,t] ----------------
// grid: B*T blocks, 256 threads = 4 waves; each wave loops 4 heads
__global__ __launch_bounds__(256) void y_kernel(
        const float* __restrict__ Qr, const float* __restrict__ KV,
        const float* __restrict__ denom, float* __restrict__ y) {
    int row = blockIdx.x;
    int b = row >> 11;
    int t = row & (Tq - 1);
    int lane = threadIdx.x & 63, w = threadIdx.x >> 6;
    __shared__ float shq[4][64];
    for (int hi = 0; hi < 4; ++hi) {
        int h = w + hi * 4;
        shq[w][lane] = Qr[(size_t)row * Cq + h * 64 + lane];
        __syncthreads();
        const float* kvp = KV + (size_t)(b * Hq + h) * 4096;
        float acc = 0.0f;
        #pragma unroll
        for (int d = 0; d < 64; ++d) acc += shq[w][d] * kvp[d * 64 + lane];
        float dn = denom[(size_t)(b * Hq + h) * Tq + t];
        y[(size_t)row * Cq + h * 64 + lane] = acc / dn;
        __syncthreads();
    }
}

extern "C" void kernel_launch(void* const* d_in, const int* in_sizes, int n_in,
                              void* d_out, int out_size, void* d_ws, size_t ws_size,
                              hipStream_t stream) {
    const float* x      = (const float*)d_in[0];
    const float* w_attn = (const float*)d_in[1];
    const float* b_attn = (const float*)d_in[2];
    const float* w_proj = (const float*)d_in[3];
    const float* b_proj = (const float*)d_in[4];
    float* out = (float*)d_out;

    float* ws = (float*)d_ws;
    float* qkv   = ws;                       // 4096*3072 = 12,582,912
    float* Qr    = qkv  + (size_t)NROW * N3C;    // 4,194,304
    float* Kr    = Qr   + (size_t)NROW * Cq;     // 4,194,304
    float* yb    = Kr   + (size_t)NROW * Cq;     // 4,194,304
    float* cosT  = yb   + (size_t)NROW * Cq;     // 65,536
    float* sinT  = cosT + Tq * 32;               // 65,536
    float* Ksum  = sinT + Tq * 32;               // 2,048
    float* denom = Ksum + Bq * Hq * Dq;          // 65,536
    float* KVp   = denom + (size_t)Bq * Hq * Tq; // 512*4096 = 2,097,152
    float* KV    = KVp  + (size_t)Bq * Hq * NCH * 4096;  // 131,072

    // 1. RoPE tables
    rope_table_kernel<<<(Tq * 32 + 255) / 256, 256, 0, stream>>>(cosT, sinT);

    // 2. qkv = x @ w_attn + b_attn    [4096,1024]@[1024,3072]
    {
        dim3 grid(N3C / BN, NROW / BM);
        gemm_bias_kernel<<<grid, 256, 0, stream>>>(x, w_attn, b_attn, qkv, NROW, N3C, Cq);
    }

    // 3. elu+1 + rope -> Qr, Kr
    qk_rope_kernel<<<NROW, 256, 0, stream>>>(qkv, cosT, sinT, Qr, Kr);

    // 4. K_sum
    ksum_kernel<<<Bq * Hq, 256, 0, stream>>>(qkv, Ksum);

    // 5. denom
    denom_kernel<<<NROW, 256, 0, stream>>>(qkv, Ksum, denom);

    // 6. KV = Kr^T @ V per head (chunked partials + reduce)
    kv_kernel<<<Bq * Hq * NCH, 256, 0, stream>>>(qkv, Kr, KVp);
    kv_reduce_kernel<<<(Bq * Hq * 4096) / 256, 256, 0, stream>>>(KVp, KV);

    // 7. y = Qr @ KV / denom
    y_kernel<<<NROW, 256, 0, stream>>>(Qr, KV, denom, yb);

    // 8. out = y @ w_proj + b_proj    [4096,1024]@[1024,1024]
    {
        dim3 grid(Cq / BN, NROW / BM);
        gemm_bias_kernel<<<grid, 256, 0, stream>>>(yb, w_proj, b_proj, out, NROW, Cq, Cq);
    }
}

// Round 2
// 443.701 us; speedup vs baseline: 1.7663x; 1.7663x over previous
//
#include <hip/hip_runtime.h>
#include <hip/hip_bf16.h>

// Problem constants (fixed by setup_inputs)
#define Bq 2
#define Tq 2048
#define Cq 1024
#define Hq 16
#define N3C 3072
#define NROW (Bq * Tq)   // 4096

typedef __attribute__((ext_vector_type(8))) __bf16 bf16x8;
typedef __attribute__((ext_vector_type(4))) float f32x4;

__device__ __forceinline__ float elu1(float x) {
    return x > 0.0f ? x + 1.0f : __expf(x);
}

// round-to-nearest-even fp32 -> bf16 bits (inputs are finite, no NaN handling)
__device__ __forceinline__ unsigned short bf16_rne(float v) {
    unsigned int u = __float_as_uint(v);
    u += 0x7FFFu + ((u >> 16) & 1u);
    return (unsigned short)(u >> 16);
}

// ---------------- RoPE cos/sin table (fp64 for accuracy) ----------------
__global__ void rope_table_kernel(float* __restrict__ cosT, float* __restrict__ sinT) {
    int idx = blockIdx.x * blockDim.x + threadIdx.x;   // T*32
    if (idx >= Tq * 32) return;
    int t = idx >> 5;
    int i = idx & 31;
    double inv = pow(10000.0, -(double)i / 32.0);
    double ang = (double)t * inv;
    cosT[idx] = (float)cos(ang);
    sinT[idx] = (float)sin(ang);
}

// ---------------- split fp32 -> bf16 hi/lo (same layout) ----------------
__global__ __launch_bounds__(256) void split_a_kernel(
        const float* __restrict__ in, unsigned short* __restrict__ hi,
        unsigned short* __restrict__ lo, int n4) {
    int idx = blockIdx.x * 256 + threadIdx.x;
    if (idx >= n4) return;
    float4 v = ((const float4*)in)[idx];
    float a[4] = {v.x, v.y, v.z, v.w};
    unsigned short hb[4], lb[4];
    #pragma unroll
    for (int i = 0; i < 4; ++i) {
        hb[i] = bf16_rne(a[i]);
        float hf = __uint_as_float((unsigned int)hb[i] << 16);
        lb[i] = bf16_rne(a[i] - hf);
    }
    ((ushort4*)hi)[idx] = make_ushort4(hb[0], hb[1], hb[2], hb[3]);
    ((ushort4*)lo)[idx] = make_ushort4(lb[0], lb[1], lb[2], lb[3]);
}

// ---------------- transpose + split: B[K][N] fp32 -> Bt_hi/lo[N][K] bf16 ----------------
__global__ __launch_bounds__(256) void split_bt_kernel(
        const float* __restrict__ B, unsigned short* __restrict__ hi,
        unsigned short* __restrict__ lo, int K, int N) {
    __shared__ float tile[32][33];
    int tx = threadIdx.x & 31, ty = threadIdx.x >> 5;    // ty 0..7
    int k0 = blockIdx.y * 32, n0 = blockIdx.x * 32;
    #pragma unroll
    for (int i = 0; i < 4; ++i)
        tile[ty + i * 8][tx] = B[(size_t)(k0 + ty + i * 8) * N + n0 + tx];
    __syncthreads();
    #pragma unroll
    for (int i = 0; i < 4; ++i) {
        int n = n0 + ty + i * 8;
        float v = tile[tx][ty + i * 8];
        unsigned short hb = bf16_rne(v);
        float hf = __uint_as_float((unsigned int)hb << 16);
        unsigned short lb = bf16_rne(v - hf);
        hi[(size_t)n * K + k0 + tx] = hb;
        lo[(size_t)n * K + k0 + tx] = lb;
    }
}

// ---------------- async global->LDS, 16B per lane ----------------
__device__ __forceinline__ void gload16(const void* g, void* l) {
    __builtin_amdgcn_global_load_lds(
        (const __attribute__((address_space(1))) void*)g,
        (__attribute__((address_space(3))) void*)l, 16, 0, 0);
}

// ---------------- split-precision bf16x3 MFMA GEMM ----------------
// C[M][N] = A[M][K] * B[K][N] + bias, where A = Ahi+Alo (bf16, row-major [M][K])
// and B supplied transposed: Bhi/Blo are [N][K] bf16.
// Tile 128x128, BK=32, 256 threads = 4 waves (2x2), each wave 64x64 = 4x4 frags.
__global__ __launch_bounds__(256) void gemm_split3_kernel(
        const unsigned short* __restrict__ Ahi, const unsigned short* __restrict__ Alo,
        const unsigned short* __restrict__ Bhi, const unsigned short* __restrict__ Blo,
        const float* __restrict__ bias, float* __restrict__ C,
        int M, int N, int K) {
    __shared__ unsigned short sAh[128][32];
    __shared__ unsigned short sAl[128][32];
    __shared__ unsigned short sBh[128][32];
    __shared__ unsigned short sBl[128][32];

    const int tid = threadIdx.x;
    const int lane = tid & 63;
    const int wave = tid >> 6;            // 0..3
    const int wr = wave >> 1, wc = wave & 1;
    const int brow = blockIdx.y * 128;
    const int bcol = blockIdx.x * 128;

    const int srow = (wave << 4) + (lane >> 2);   // staging row 0..63 per it
    const int skc = (lane & 3) << 3;              // staging k offset (bf16 elems)

    const int fr = lane & 15;                     // fragment row (m or n)
    const int fk = (lane >> 4) << 3;              // fragment k offset

    f32x4 acc[4][4];
    #pragma unroll
    for (int i = 0; i < 4; ++i)
        #pragma unroll
        for (int j = 0; j < 4; ++j)
            acc[i][j] = (f32x4){0.0f, 0.0f, 0.0f, 0.0f};

    for (int k0 = 0; k0 < K; k0 += 32) {
        #pragma unroll
        for (int it = 0; it < 2; ++it) {
            int r = (it << 6) + srow;
            size_t ga = (size_t)(brow + r) * K + k0 + skc;
            size_t gb = (size_t)(bcol + r) * K + k0 + skc;
            int lr = (it << 6) + (wave << 4);     // wave-uniform LDS row base
            gload16(Ahi + ga, &sAh[lr][0]);
            gload16(Alo + ga, &sAl[lr][0]);
            gload16(Bhi + gb, &sBh[lr][0]);
            gload16(Blo + gb, &sBl[lr][0]);
        }
        __syncthreads();

        bf16x8 ah[4], al[4], bh[4], bl[4];
        #pragma unroll
        for (int i = 0; i < 4; ++i) {
            ah[i] = *(const bf16x8*)&sAh[(wr << 6) + (i << 4) + fr][fk];
            al[i] = *(const bf16x8*)&sAl[(wr << 6) + (i << 4) + fr][fk];
            bh[i] = *(const bf16x8*)&sBh[(wc << 6) + (i << 4) + fr][fk];
            bl[i] = *(const bf16x8*)&sBl[(wc << 6) + (i << 4) + fr][fk];
        }
        #pragma unroll
        for (int i = 0; i < 4; ++i)
            #pragma unroll
            for (int j = 0; j < 4; ++j) {
                acc[i][j] = __builtin_amdgcn_mfma_f32_16x16x32_bf16(ah[i], bh[j], acc[i][j], 0, 0, 0);
                acc[i][j] = __builtin_amdgcn_mfma_f32_16x16x32_bf16(ah[i], bl[j], acc[i][j], 0, 0, 0);
                acc[i][j] = __builtin_amdgcn_mfma_f32_16x16x32_bf16(al[i], bh[j], acc[i][j], 0, 0, 0);
            }
        __syncthreads();
    }

    // C/D layout: col = lane&15, row = (lane>>4)*4 + q  [m89/m91 verified]
    #pragma unroll
    for (int j = 0; j < 4; ++j) {
        int n = bcol + (wc << 6) + (j << 4) + fr;
        float bv = bias[n];
        #pragma unroll
        for (int i = 0; i < 4; ++i) {
            int m = brow + (wr << 6) + (i << 4) + ((lane >> 4) << 2);
            #pragma unroll
            for (int q = 0; q < 4; ++q)
                C[(size_t)(m + q) * N + n] = acc[i][j][q] + bv;
        }
    }
}

// ---------------- elu+1 then RoPE for Q and K ----------------
__global__ __launch_bounds__(256) void qk_rope_kernel(
        const float* __restrict__ qkv, const float* __restrict__ cosT,
        const float* __restrict__ sinT, float* __restrict__ Qr,
        float* __restrict__ Kr) {
    int row = blockIdx.x;          // b*T + t
    int t = row & (Tq - 1);
    const float* q = qkv + (size_t)row * N3C;
    #pragma unroll
    for (int i = 0; i < 4; ++i) {
        int idx = threadIdx.x + i * 256;      // 0..1023 = h*64+d
        int d = idx & 63;
        int p = (d < 32) ? idx + 32 : idx - 32;
        float c = cosT[t * 32 + (d & 31)];
        float s = sinT[t * 32 + (d & 31)];
        float sgn = (d < 32) ? -1.0f : 1.0f;
        float qv = elu1(q[idx]);
        float qp = elu1(q[p]);
        float kv = elu1(q[Cq + idx]);
        float kp = elu1(q[Cq + p]);
        Qr[(size_t)row * Cq + idx] = qv * c + sgn * qp * s;
        Kr[(size_t)row * Cq + idx] = kv * c + sgn * kp * s;
    }
}

// ---------------- K_sum[b,h,d] = sum_t elu1(K) (deterministic) ----------------
__global__ __launch_bounds__(256) void ksum_kernel(
        const float* __restrict__ qkv, float* __restrict__ Ksum) {
    int bh = blockIdx.x;
    int b = bh >> 4, h = bh & 15;
    int lane = threadIdx.x & 63, w = threadIdx.x >> 6;
    float s = 0.0f;
    for (int t = w; t < Tq; t += 4)
        s += elu1(qkv[((size_t)(b * Tq + t)) * N3C + Cq + h * 64 + lane]);
    __shared__ float red[4][64];
    red[w][lane] = s;
    __syncthreads();
    if (w == 0)
        Ksum[bh * 64 + lane] = red[0][lane] + red[1][lane] + red[2][lane] + red[3][lane];
}

// ---------------- denom[b,h,t] = dot(elu1(Q[b,t,h,:]), Ksum[b,h,:]) ----------------
__global__ __launch_bounds__(256) void denom_kernel(
        const float* __restrict__ qkv, const float* __restrict__ Ksum,
        float* __restrict__ denom) {
    int row = blockIdx.x;
    int b = row >> 11;
    int t = row & (Tq - 1);
    int lane = threadIdx.x & 63, w = threadIdx.x >> 6;
    #pragma unroll
    for (int hi = 0; hi < 4; ++hi) {
        int h = w * 4 + hi;
        float v = elu1(qkv[(size_t)row * N3C + h * 64 + lane]) * Ksum[(b * Hq + h) * 64 + lane];
        #pragma unroll
        for (int off = 32; off; off >>= 1) v += __shfl_down(v, off);
        if (lane == 0) denom[(size_t)(b * Hq + h) * Tq + t] = v;
    }
}

// ---------------- KV partial: KVpart[bh,ch,d,e] = sum_{t in chunk} Kr[t,d]*V[t,e] ----------------
#define NCH 16
#define CHT (Tq / NCH)    // 128
__global__ __launch_bounds__(256) void kv_kernel(
        const float* __restrict__ qkv, const float* __restrict__ Kr,
        float* __restrict__ KVpart) {
    int blk = blockIdx.x;                 // bh*NCH + ch
    int bh = blk / NCH, ch = blk % NCH;
    int b = bh >> 4, h = bh & 15;
    int e = threadIdx.x & 63;
    int dq = threadIdx.x >> 6;            // 0..3
    float acc[16] = {};
    __shared__ float sh[128];
    for (int tt = 0; tt < CHT; ++tt) {
        int t = ch * CHT + tt;
        size_t row = (size_t)(b * Tq + t);
        if (threadIdx.x < 64)
            sh[threadIdx.x] = Kr[row * Cq + h * 64 + threadIdx.x];
        else if (threadIdx.x < 128)
            sh[threadIdx.x] = qkv[row * N3C + 2 * Cq + h * 64 + (threadIdx.x - 64)];
        __syncthreads();
        float vv = sh[64 + e];
        #pragma unroll
        for (int i = 0; i < 16; ++i) acc[i] += sh[dq * 16 + i] * vv;
        __syncthreads();
    }
    float* out = KVpart + (size_t)blk * 4096;
    #pragma unroll
    for (int i = 0; i < 16; ++i) out[(dq * 16 + i) * 64 + e] = acc[i];
}

// ---------------- KV reduce over chunks ----------------
__global__ __launch_bounds__(256) void kv_reduce_kernel(
        const float* __restrict__ KVpart, float* __restrict__ KV) {
    int idx = blockIdx.x * 256 + threadIdx.x;    // < B*H*4096 = 131072
    int bh = idx >> 12;
    int i = idx & 4095;
    float s = 0.0f;
    #pragma unroll
    for (int ch = 0; ch < NCH; ++ch) s += KVpart[((size_t)(bh * NCH + ch)) * 4096 + i];
    KV[idx] = s;
}

// ---------------- y[b,t,h,e] = (sum_d Qr[t,d]*KV[d,e]) / denom[b,h,t] ----------------
__global__ __launch_bounds__(256) void y_kernel(
        const float* __restrict__ Qr, const float* __restrict__ KV,
        const float* __restrict__ denom, float* __restrict__ y) {
    int row = blockIdx.x;
    int b = row >> 11;
    int t = row & (Tq - 1);
    int lane = threadIdx.x & 63, w = threadIdx.x >> 6;
    __shared__ float shq[4][64];
    for (int hi = 0; hi < 4; ++hi) {
        int h = w + hi * 4;
        shq[w][lane] = Qr[(size_t)row * Cq + h * 64 + lane];
        __syncthreads();
        const float* kvp = KV + (size_t)(b * Hq + h) * 4096;
        float acc = 0.0f;
        #pragma unroll
        for (int d = 0; d < 64; ++d) acc += shq[w][d] * kvp[d * 64 + lane];
        float dn = denom[(size_t)(b * Hq + h) * Tq + t];
        y[(size_t)row * Cq + h * 64 + lane] = acc / dn;
        __syncthreads();
    }
}

extern "C" void kernel_launch(void* const* d_in, const int* in_sizes, int n_in,
                              void* d_out, int out_size, void* d_ws, size_t ws_size,
                              hipStream_t stream) {
    const float* x      = (const float*)d_in[0];
    const float* w_attn = (const float*)d_in[1];
    const float* b_attn = (const float*)d_in[2];
    const float* w_proj = (const float*)d_in[3];
    const float* b_proj = (const float*)d_in[4];
    float* out = (float*)d_out;

    float* ws = (float*)d_ws;
    float* qkv   = ws;                           // 12,582,912
    float* Qr    = qkv  + (size_t)NROW * N3C;    // 4,194,304
    float* Kr    = Qr   + (size_t)NROW * Cq;     // 4,194,304
    float* yb    = Kr   + (size_t)NROW * Cq;     // 4,194,304
    float* cosT  = yb   + (size_t)NROW * Cq;     // 65,536
    float* sinT  = cosT + Tq * 32;               // 65,536
    float* Ksum  = sinT + Tq * 32;               // 2,048
    float* denom = Ksum + 2048;                  // 65,536
    float* KVp   = denom + 65536;                // 2,097,152
    float* KV    = KVp  + 2097152;               // 131,072
    unsigned short* xhi  = (unsigned short*)(KV + 131072);   // 4,194,304 shorts (also reused for yb)
    unsigned short* xlo  = xhi + (size_t)NROW * Cq;
    unsigned short* wahi = xlo + (size_t)NROW * Cq;          // 3,145,728
    unsigned short* walo = wahi + (size_t)N3C * Cq;
    unsigned short* wphi = walo + (size_t)N3C * Cq;          // 1,048,576
    unsigned short* wplo = wphi + (size_t)Cq * Cq;

    // 1. RoPE tables
    rope_table_kernel<<<(Tq * 32 + 255) / 256, 256, 0, stream>>>(cosT, sinT);

    // 2. split inputs for GEMM1
    split_a_kernel<<<(NROW * Cq / 4 + 255) / 256, 256, 0, stream>>>(x, xhi, xlo, NROW * Cq / 4);
    split_bt_kernel<<<dim3(N3C / 32, Cq / 32), 256, 0, stream>>>(w_attn, wahi, walo, Cq, N3C);

    // 3. qkv = x @ w_attn + b_attn  (bf16x3 MFMA)
    gemm_split3_kernel<<<dim3(N3C / 128, NROW / 128), 256, 0, stream>>>(
        xhi, xlo, wahi, walo, b_attn, qkv, NROW, N3C, Cq);

    // 4. elu+1 + rope -> Qr, Kr
    qk_rope_kernel<<<NROW, 256, 0, stream>>>(qkv, cosT, sinT, Qr, Kr);

    // 5. K_sum
    ksum_kernel<<<Bq * Hq, 256, 0, stream>>>(qkv, Ksum);

    // 6. denom
    denom_kernel<<<NROW, 256, 0, stream>>>(qkv, Ksum, denom);

    // 7. KV = Kr^T @ V per head (chunked partials + reduce)
    kv_kernel<<<Bq * Hq * NCH, 256, 0, stream>>>(qkv, Kr, KVp);
    kv_reduce_kernel<<<(Bq * Hq * 4096) / 256, 256, 0, stream>>>(KVp, KV);

    // 8. y = Qr @ KV / denom
    y_kernel<<<NROW, 256, 0, stream>>>(Qr, KV, denom, yb);

    // 9. split y + w_proj, then out = y @ w_proj + b_proj
    split_a_kernel<<<(NROW * Cq / 4 + 255) / 256, 256, 0, stream>>>(yb, xhi, xlo, NROW * Cq / 4);
    split_bt_kernel<<<dim3(Cq / 32, Cq / 32), 256, 0, stream>>>(w_proj, wphi, wplo, Cq, Cq);
    gemm_split3_kernel<<<dim3(Cq / 128, NROW / 128), 256, 0, stream>>>(
        xhi, xlo, wphi, wplo, b_proj, out, NROW, Cq, Cq);
}

// Round 3
// 257.642 us; speedup vs baseline: 3.0418x; 1.7222x over previous
//
#include <hip/hip_runtime.h>
#include <hip/hip_bf16.h>

// Problem constants (fixed by setup_inputs)
#define Bq 2
#define Tq 2048
#define Cq 1024
#define Hq 16
#define N3C 3072
#define NROW (Bq * Tq)   // 4096

typedef __attribute__((ext_vector_type(8))) __bf16 bf16x8;
typedef __attribute__((ext_vector_type(4))) float f32x4;

__device__ __forceinline__ float elu1(float x) {
    return x > 0.0f ? x + 1.0f : __expf(x);
}

// round-to-nearest-even fp32 -> bf16 bits (inputs are finite, no NaN handling)
__device__ __forceinline__ unsigned short bf16_rne(float v) {
    unsigned int u = __float_as_uint(v);
    u += 0x7FFFu + ((u >> 16) & 1u);
    return (unsigned short)(u >> 16);
}

// ---------------- RoPE cos/sin table (fp64 for accuracy) ----------------
__global__ void rope_table_kernel(float* __restrict__ cosT, float* __restrict__ sinT) {
    int idx = blockIdx.x * blockDim.x + threadIdx.x;   // T*32
    if (idx >= Tq * 32) return;
    int t = idx >> 5;
    int i = idx & 31;
    double inv = pow(10000.0, -(double)i / 32.0);
    double ang = (double)t * inv;
    cosT[idx] = (float)cos(ang);
    sinT[idx] = (float)sin(ang);
}

// ---------------- split fp32 -> bf16 hi/lo (same layout) ----------------
__global__ __launch_bounds__(256) void split_a_kernel(
        const float* __restrict__ in, unsigned short* __restrict__ hi,
        unsigned short* __restrict__ lo, int n4) {
    int idx = blockIdx.x * 256 + threadIdx.x;
    if (idx >= n4) return;
    float4 v = ((const float4*)in)[idx];
    float a[4] = {v.x, v.y, v.z, v.w};
    unsigned short hb[4], lb[4];
    #pragma unroll
    for (int i = 0; i < 4; ++i) {
        hb[i] = bf16_rne(a[i]);
        float hf = __uint_as_float((unsigned int)hb[i] << 16);
        lb[i] = bf16_rne(a[i] - hf);
    }
    ((ushort4*)hi)[idx] = make_ushort4(hb[0], hb[1], hb[2], hb[3]);
    ((ushort4*)lo)[idx] = make_ushort4(lb[0], lb[1], lb[2], lb[3]);
}

// ---------------- transpose + split: B[K][N] fp32 -> Bt_hi/lo[N][K] bf16 ----------------
__global__ __launch_bounds__(256) void split_bt_kernel(
        const float* __restrict__ B, unsigned short* __restrict__ hi,
        unsigned short* __restrict__ lo, int K, int N) {
    __shared__ float tile[32][33];
    int tx = threadIdx.x & 31, ty = threadIdx.x >> 5;    // ty 0..7
    int k0 = blockIdx.y * 32, n0 = blockIdx.x * 32;
    #pragma unroll
    for (int i = 0; i < 4; ++i)
        tile[ty + i * 8][tx] = B[(size_t)(k0 + ty + i * 8) * N + n0 + tx];
    __syncthreads();
    #pragma unroll
    for (int i = 0; i < 4; ++i) {
        int n = n0 + ty + i * 8;
        float v = tile[tx][ty + i * 8];
        unsigned short hb = bf16_rne(v);
        float hf = __uint_as_float((unsigned int)hb << 16);
        unsigned short lb = bf16_rne(v - hf);
        hi[(size_t)n * K + k0 + tx] = hb;
        lo[(size_t)n * K + k0 + tx] = lb;
    }
}

// ---------------- async global->LDS, 16B per lane ----------------
__device__ __forceinline__ void gload16(const void* g, void* l) {
    __builtin_amdgcn_global_load_lds(
        (const __attribute__((address_space(1))) void*)g,
        (__attribute__((address_space(3))) void*)l, 16, 0, 0);
}

// ---------------- split-precision bf16x3 MFMA GEMM ----------------
// C[M][N] = A[M][K] * B[K][N] + bias, where A = Ahi+Alo (bf16, row-major [M][K])
// and B supplied transposed: Bhi/Blo are [N][K] bf16.
// Tile 128x128, BK=32, 256 threads = 4 waves (2x2), each wave 64x64 = 4x4 frags.
__global__ __launch_bounds__(256) void gemm_split3_kernel(
        const unsigned short* __restrict__ Ahi, const unsigned short* __restrict__ Alo,
        const unsigned short* __restrict__ Bhi, const unsigned short* __restrict__ Blo,
        const float* __restrict__ bias, float* __restrict__ C,
        int M, int N, int K) {
    __shared__ unsigned short sAh[128][32];
    __shared__ unsigned short sAl[128][32];
    __shared__ unsigned short sBh[128][32];
    __shared__ unsigned short sBl[128][32];

    const int tid = threadIdx.x;
    const int lane = tid & 63;
    const int wave = tid >> 6;            // 0..3
    const int wr = wave >> 1, wc = wave & 1;
    const int brow = blockIdx.y * 128;
    const int bcol = blockIdx.x * 128;

    const int srow = (wave << 4) + (lane >> 2);   // staging row 0..63 per it
    const int skc = (lane & 3) << 3;              // staging k offset (bf16 elems)

    const int fr = lane & 15;                     // fragment row (m or n)
    const int fk = (lane >> 4) << 3;              // fragment k offset

    f32x4 acc[4][4];
    #pragma unroll
    for (int i = 0; i < 4; ++i)
        #pragma unroll
        for (int j = 0; j < 4; ++j)
            acc[i][j] = (f32x4){0.0f, 0.0f, 0.0f, 0.0f};

    for (int k0 = 0; k0 < K; k0 += 32) {
        #pragma unroll
        for (int it = 0; it < 2; ++it) {
            int r = (it << 6) + srow;
            size_t ga = (size_t)(brow + r) * K + k0 + skc;
            size_t gb = (size_t)(bcol + r) * K + k0 + skc;
            int lr = (it << 6) + (wave << 4);     // wave-uniform LDS row base
            gload16(Ahi + ga, &sAh[lr][0]);
            gload16(Alo + ga, &sAl[lr][0]);
            gload16(Bhi + gb, &sBh[lr][0]);
            gload16(Blo + gb, &sBl[lr][0]);
        }
        __syncthreads();

        bf16x8 ah[4], al[4], bh[4], bl[4];
        #pragma unroll
        for (int i = 0; i < 4; ++i) {
            ah[i] = *(const bf16x8*)&sAh[(wr << 6) + (i << 4) + fr][fk];
            al[i] = *(const bf16x8*)&sAl[(wr << 6) + (i << 4) + fr][fk];
            bh[i] = *(const bf16x8*)&sBh[(wc << 6) + (i << 4) + fr][fk];
            bl[i] = *(const bf16x8*)&sBl[(wc << 6) + (i << 4) + fr][fk];
        }
        #pragma unroll
        for (int i = 0; i < 4; ++i)
            #pragma unroll
            for (int j = 0; j < 4; ++j) {
                acc[i][j] = __builtin_amdgcn_mfma_f32_16x16x32_bf16(ah[i], bh[j], acc[i][j], 0, 0, 0);
                acc[i][j] = __builtin_amdgcn_mfma_f32_16x16x32_bf16(ah[i], bl[j], acc[i][j], 0, 0, 0);
                acc[i][j] = __builtin_amdgcn_mfma_f32_16x16x32_bf16(al[i], bh[j], acc[i][j], 0, 0, 0);
            }
        __syncthreads();
    }

    // C/D layout: col = lane&15, row = (lane>>4)*4 + q  [m89/m91 verified]
    #pragma unroll
    for (int j = 0; j < 4; ++j) {
        int n = bcol + (wc << 6) + (j << 4) + fr;
        float bv = bias[n];
        #pragma unroll
        for (int i = 0; i < 4; ++i) {
            int m = brow + (wr << 6) + (i << 4) + ((lane >> 4) << 2);
            #pragma unroll
            for (int q = 0; q < 4; ++q)
                C[(size_t)(m + q) * N + n] = acc[i][j][q] + bv;
        }
    }
}

// ---------------- K_sum two-stage deterministic reduction ----------------
#define KCH 32
#define KCHT (Tq / KCH)    // 64
__global__ __launch_bounds__(256) void ksum_part_kernel(
        const float* __restrict__ qkv, float* __restrict__ Kpart) {
    int blk = blockIdx.x;                 // bh*KCH + ch
    int bh = blk >> 5, ch = blk & 31;
    int b = bh >> 4, h = bh & 15;
    int lane = threadIdx.x & 63, w = threadIdx.x >> 6;
    float s = 0.0f;
    for (int tt = w; tt < KCHT; tt += 4) {
        int t = ch * KCHT + tt;
        s += elu1(qkv[(size_t)(b * Tq + t) * N3C + Cq + h * 64 + lane]);
    }
    __shared__ float red[4][64];
    red[w][lane] = s;
    __syncthreads();
    if (w == 0)
        Kpart[(size_t)blk * 64 + lane] = red[0][lane] + red[1][lane] + red[2][lane] + red[3][lane];
}

__global__ __launch_bounds__(256) void ksum_final_kernel(
        const float* __restrict__ Kpart, float* __restrict__ Ksum) {
    int idx = blockIdx.x * 256 + threadIdx.x;    // < B*H*64 = 2048
    if (idx >= Bq * Hq * 64) return;
    int bh = idx >> 6, d = idx & 63;
    float s = 0.0f;
    #pragma unroll
    for (int ch = 0; ch < KCH; ++ch) s += Kpart[(size_t)(bh * KCH + ch) * 64 + d];
    Ksum[idx] = s;
}

// ---------------- fused: elu+1 + RoPE for Q,K AND denom ----------------
// grid: B*T blocks, 256 threads. idx = tid + i*256 -> head = 4i+w, d = lane,
// so the denom dot for head 4i+w is a single wave shuffle-reduce.
__global__ __launch_bounds__(256) void rope_denom_kernel(
        const float* __restrict__ qkv, const float* __restrict__ cosT,
        const float* __restrict__ sinT, const float* __restrict__ Ksum,
        float* __restrict__ Qr, float* __restrict__ Kr,
        float* __restrict__ denom) {
    int row = blockIdx.x;          // b*T + t
    int b = row >> 11;
    int t = row & (Tq - 1);
    int lane = threadIdx.x & 63, w = threadIdx.x >> 6;
    const float* q = qkv + (size_t)row * N3C;
    #pragma unroll
    for (int i = 0; i < 4; ++i) {
        int idx = threadIdx.x + i * 256;      // 0..1023 = h*64+d
        int d = idx & 63;                     // == lane
        int p = (d < 32) ? idx + 32 : idx - 32;
        float c = cosT[t * 32 + (d & 31)];
        float s = sinT[t * 32 + (d & 31)];
        float sgn = (d < 32) ? -1.0f : 1.0f;
        float qv = elu1(q[idx]);
        float qp = elu1(q[p]);
        float kv = elu1(q[Cq + idx]);
        float kp = elu1(q[Cq + p]);
        Qr[(size_t)row * Cq + idx] = qv * c + sgn * qp * s;
        Kr[(size_t)row * Cq + idx] = kv * c + sgn * kp * s;
        int h = (i << 2) + w;
        float prod = qv * Ksum[(b * Hq + h) * 64 + lane];
        #pragma unroll
        for (int off = 32; off; off >>= 1) prod += __shfl_down(prod, off);
        if (lane == 0) denom[(size_t)(b * Hq + h) * Tq + t] = prod;
    }
}

// ---------------- KV partial: KVpart[bh,ch,d,e] = sum_{t in chunk} Kr[t,d]*V[t,e] ----------------
#define NCH 16
#define CHT (Tq / NCH)    // 128
__global__ __launch_bounds__(256) void kv_kernel(
        const float* __restrict__ qkv, const float* __restrict__ Kr,
        float* __restrict__ KVpart) {
    int blk = blockIdx.x;                 // bh*NCH + ch
    int bh = blk / NCH, ch = blk % NCH;
    int b = bh >> 4, h = bh & 15;
    int e = threadIdx.x & 63;
    int dq = threadIdx.x >> 6;            // 0..3
    int u = threadIdx.x >> 7;             // 0: load K, 1: load V
    int r2l = (threadIdx.x >> 6) & 1;     // which of 2 rows
    int j = threadIdx.x & 63;
    float acc[16] = {};
    __shared__ float sh[2][2][64];        // [r2][K/V][j]
    for (int tt = 0; tt < CHT; tt += 2) {
        int t = ch * CHT + tt + r2l;
        size_t row = (size_t)(b * Tq + t);
        sh[r2l][u][j] = (u == 0) ? Kr[row * Cq + h * 64 + j]
                                 : qkv[row * N3C + 2 * Cq + h * 64 + j];
        __syncthreads();
        #pragma unroll
        for (int r2 = 0; r2 < 2; ++r2) {
            float vv = sh[r2][1][e];
            #pragma unroll
            for (int i2 = 0; i2 < 16; ++i2) acc[i2] += sh[r2][0][dq * 16 + i2] * vv;
        }
        __syncthreads();
    }
    float* out = KVpart + (size_t)blk * 4096;
    #pragma unroll
    for (int i2 = 0; i2 < 16; ++i2) out[(dq * 16 + i2) * 64 + e] = acc[i2];
}

// ---------------- KV reduce over chunks ----------------
__global__ __launch_bounds__(256) void kv_reduce_kernel(
        const float* __restrict__ KVpart, float* __restrict__ KV) {
    int idx = blockIdx.x * 256 + threadIdx.x;    // < B*H*4096 = 131072
    int bh = idx >> 12;
    int i = idx & 4095;
    float s = 0.0f;
    #pragma unroll
    for (int ch = 0; ch < NCH; ++ch) s += KVpart[((size_t)(bh * NCH + ch)) * 4096 + i];
    KV[idx] = s;
}

// ---------------- y = (Qr @ KV) / denom, fused bf16 hi/lo split ----------------
__global__ __launch_bounds__(256) void y_split_kernel(
        const float* __restrict__ Qr, const float* __restrict__ KV,
        const float* __restrict__ denom, unsigned short* __restrict__ hi,
        unsigned short* __restrict__ lo) {
    int row = blockIdx.x;
    int b = row >> 11;
    int t = row & (Tq - 1);
    int lane = threadIdx.x & 63, w = threadIdx.x >> 6;
    __shared__ float shq[4][64];
    for (int hh = 0; hh < 4; ++hh) {
        int h = w + hh * 4;
        shq[w][lane] = Qr[(size_t)row * Cq + h * 64 + lane];
        __syncthreads();
        const float* kvp = KV + (size_t)(b * Hq + h) * 4096;
        float acc = 0.0f;
        #pragma unroll
        for (int d = 0; d < 64; ++d) acc += shq[w][d] * kvp[d * 64 + lane];
        float dn = denom[(size_t)(b * Hq + h) * Tq + t];
        float v = acc / dn;
        unsigned short hb = bf16_rne(v);
        float hf = __uint_as_float((unsigned int)hb << 16);
        hi[(size_t)row * Cq + h * 64 + lane] = hb;
        lo[(size_t)row * Cq + h * 64 + lane] = bf16_rne(v - hf);
        __syncthreads();
    }
}

extern "C" void kernel_launch(void* const* d_in, const int* in_sizes, int n_in,
                              void* d_out, int out_size, void* d_ws, size_t ws_size,
                              hipStream_t stream) {
    const float* x      = (const float*)d_in[0];
    const float* w_attn = (const float*)d_in[1];
    const float* b_attn = (const float*)d_in[2];
    const float* w_proj = (const float*)d_in[3];
    const float* b_proj = (const float*)d_in[4];
    float* out = (float*)d_out;

    float* ws = (float*)d_ws;
    float* qkv   = ws;                           // 12,582,912
    float* Qr    = qkv  + (size_t)NROW * N3C;    // 4,194,304
    float* Kr    = Qr   + (size_t)NROW * Cq;     // 4,194,304
    float* cosT  = Kr   + (size_t)NROW * Cq;     // 65,536
    float* sinT  = cosT + Tq * 32;               // 65,536
    float* Kpart = sinT + Tq * 32;               // 65,536 (B*H*KCH*64)
    float* Ksum  = Kpart + 65536;                // 2,048
    float* denom = Ksum + 2048;                  // 65,536
    float* KVp   = denom + 65536;                // 2,097,152
    float* KV    = KVp  + 2097152;               // 131,072
    unsigned short* xhi  = (unsigned short*)(KV + 131072);   // reused for x then y
    unsigned short* xlo  = xhi + (size_t)NROW * Cq;
    unsigned short* wahi = xlo + (size_t)NROW * Cq;          // 3,145,728
    unsigned short* walo = wahi + (size_t)N3C * Cq;
    unsigned short* wphi = walo + (size_t)N3C * Cq;          // 1,048,576
    unsigned short* wplo = wphi + (size_t)Cq * Cq;

    // 1. RoPE tables
    rope_table_kernel<<<(Tq * 32 + 255) / 256, 256, 0, stream>>>(cosT, sinT);

    // 2. split inputs for both GEMMs
    split_a_kernel<<<(NROW * Cq / 4 + 255) / 256, 256, 0, stream>>>(x, xhi, xlo, NROW * Cq / 4);
    split_bt_kernel<<<dim3(N3C / 32, Cq / 32), 256, 0, stream>>>(w_attn, wahi, walo, Cq, N3C);
    split_bt_kernel<<<dim3(Cq / 32, Cq / 32), 256, 0, stream>>>(w_proj, wphi, wplo, Cq, Cq);

    // 3. qkv = x @ w_attn + b_attn  (bf16x3 MFMA)
    gemm_split3_kernel<<<dim3(N3C / 128, NROW / 128), 256, 0, stream>>>(
        xhi, xlo, wahi, walo, b_attn, qkv, NROW, N3C, Cq);

    // 4. K_sum (two-stage, parallel, deterministic)
    ksum_part_kernel<<<Bq * Hq * KCH, 256, 0, stream>>>(qkv, Kpart);
    ksum_final_kernel<<<8, 256, 0, stream>>>(Kpart, Ksum);

    // 5. fused rope + denom
    rope_denom_kernel<<<NROW, 256, 0, stream>>>(qkv, cosT, sinT, Ksum, Qr, Kr, denom);

    // 6. KV = Kr^T @ V per head (chunked partials + reduce)
    kv_kernel<<<Bq * Hq * NCH, 256, 0, stream>>>(qkv, Kr, KVp);
    kv_reduce_kernel<<<(Bq * Hq * 4096) / 256, 256, 0, stream>>>(KVp, KV);

    // 7. y = Qr @ KV / denom, fused split into bf16 hi/lo (A of proj GEMM)
    y_split_kernel<<<NROW, 256, 0, stream>>>(Qr, KV, denom, xhi, xlo);

    // 8. out = y @ w_proj + b_proj
    gemm_split3_kernel<<<dim3(Cq / 128, NROW / 128), 256, 0, stream>>>(
        xhi, xlo, wphi, wplo, b_proj, out, NROW, Cq, Cq);
}